// Round 14
// baseline (29.475 us; speedup 1.0000x reference)
//
#include <hip/hip_runtime.h>

#define NB 64
#define NK 49
#define NL 200
#define ND 36
#define LD (NL*ND)              // 7200

// workspace layout (float offsets)
#define AT_FLOATS   (LD*NB*4)                   // At3[d][l][b][4] = {x,t,m,pd}
#define WPK_FLOATS  (LD*NK*6)                   // Wpk3[d][ks][l][42]
#define PART_FLOATS (2*NB*NK*ND)                // part[lh][b][k][d]
#define WPK_OFF    AT_FLOATS
#define PART_OFF   (AT_FLOATS + WPK_FLOATS)
#define WS_NEED_BYTES ((size_t)(AT_FLOATS + WPK_FLOATS + PART_FLOATS) * 4)

#define LOG2E 1.44269504088896f

#if __has_builtin(__builtin_amdgcn_exp2f)
#define EXP2F(x) __builtin_amdgcn_exp2f(x)
#else
#define EXP2F(x) __expf((x) * 0.6931471805599453f)
#endif

// ---------------- K1: pack activations (transpose, d-major) + weights (d-major slabs) ------
// (unchanged from R8 — proven)
__global__ __launch_bounds__(256) void alnn_pack(
    const float* __restrict__ X, const float* __restrict__ T,
    const float* __restrict__ M, const float* __restrict__ PD,
    const float* __restrict__ w_v, const float4* __restrict__ w_t,
    const float* __restrict__ b_t, float* __restrict__ ws)
{
    __shared__ float tile[9440];
    const int bid = blockIdx.x, t = threadIdx.x;

    if (bid < 225) {
        const int ld0 = bid * 32;
        const int ld = t & 31, bq = t >> 5;
        const float* src[4] = {X, T, M, PD};
        #pragma unroll
        for (int a = 0; a < 4; a++) {
            const float* A = src[a];
            for (int b = bq; b < 64; b += 8)
                tile[(a * 64 + b) * 33 + ld] = A[(size_t)b * LD + ld0 + ld];
        }
        __syncthreads();
        float4* At4 = (float4*)ws;
        const int b = t & 63, ldq = t >> 6;
        #pragma unroll
        for (int r = 0; r < 8; r++) {
            const int l_local = ldq * 8 + r;
            const int ldg = ld0 + l_local;
            const int l = ldg / ND, d = ldg - l * ND;
            float4 v;
            v.x = tile[(0 * 64 + b) * 33 + l_local];
            v.y = tile[(1 * 64 + b) * 33 + l_local];
            v.z = tile[(2 * 64 + b) * 33 + l_local];
            v.w = tile[(3 * 64 + b) * 33 + l_local];
            At4[((size_t)d * NL + l) * 64 + b] = v;
        }
    } else {
        const int ld0 = (bid - 225) * 32;
        const int ld = t & 31, kq = t >> 5;
        for (int k = kq; k < NK; k += 8) {
            const float4 wt = w_t[(size_t)k * LD + ld0 + ld];
            const float  bt = b_t[(size_t)k * LD + ld0 + ld];
            const float  wv = w_v[(size_t)k * LD + ld0 + ld];
            float* w = tile + ld * 295 + k * 6;
            w[0] = wt.x; w[1] = wt.y; w[2] = wt.z; w[3] = wt.w;
            w[4] = 4.0f * bt; w[5] = wv;
        }
        __syncthreads();
        float* Wpk = ws + WPK_OFF;
        for (int i = t; i < 7 * 32 * 42; i += 256) {
            const int ks = i / 1344, rem = i - ks * 1344;
            const int l_local = rem / 42, c = rem - l_local * 42;
            const int ldg = ld0 + l_local;
            const int l = ldg / ND, d = ldg - l * ND;
            Wpk[(((size_t)d * 7 + ks) * NL + l) * 42 + c] =
                tile[l_local * 295 + ks * 42 + c];
        }
    }
}

// ---------------- K2: 2 blocks/CU (8 waves/SIMD), halved serial chain, depth-2 pipeline ----
// grid 504 = (d:36) x (ks:7) x (lh:2); block 1024 = 16 waves; lane=b; wave: 6-7 l x 7 k.
__global__ __launch_bounds__(1024, 8) void alnn_main10(
    const float* __restrict__ ws_ro, const float* __restrict__ alpha,
    float* __restrict__ part)
{
    __shared__ float red[16 * 7 * 64];                   // 28,672 B (2 blocks/CU -> 57 KB)

    // bijective XCD swizzle (nwg=504 = 8*63 exact): d-major job order keeps the
    // 14 jobs of one d on (mostly) one XCD -> At d-slab pulled into one L2.
    const int orig = blockIdx.x;
    const int job  = (orig & 7) * 63 + (orig >> 3);
    const int d    = job / 14;
    const int r14  = job - d * 14;
    const int ks   = r14 >> 1, lh = r14 & 1;

    const int t  = threadIdx.x;
    const int b  = t & 63;
    const int w  = __builtin_amdgcn_readfirstlane(t >> 6);   // wave id 0..15 (SGPR)
    const int k0 = ks * 7;

    const float4* At4 = (const float4*)ws_ro + (size_t)d * NL * 64;
    const float*  Ws  = ws_ro + WPK_OFF + ((size_t)d * 7 + ks) * NL * 42;

    float arn[7], rk[7];
    #pragma unroll
    for (int kk = 0; kk < 7; kk++) {
        arn[kk] = -fmaxf(alpha[k0 + kk], 0.0f) * LOG2E;
        rk[kk]  = (float)(k0 + kk);
    }

    float acc[7] = {0, 0, 0, 0, 0, 0, 0};

    // wave covers 6-7 l's of this block's 100-l half
    const int len  = (w < 4) ? 7 : 6;
    const int lbeg = lh * 100 + ((w < 4) ? 7 * w : 28 + 6 * (w - 4));

    // depth-2 software pipeline on the At4 chain
    float4 av = At4[(size_t)lbeg * 64 + b];
    for (int ll = 0; ll < len; ll++) {
        const int l = lbeg + ll;
        float4 nxt = av;
        if (ll + 1 < len) nxt = At4[(size_t)(l + 1) * 64 + b];
        const float xp = fmaxf(av.x, 0.0f);              // relu(x*e) == relu(x)*e, e>0
        const float* wr = Ws + (size_t)l * 42;           // wave-uniform -> s_load
        #pragma unroll
        for (int kk = 0; kk < 7; kk++) {
            const float dist = fabsf(av.y - rk[kk]);
            const float e    = EXP2F(arn[kk] * dist);
            float s = fmaf(wr[kk*6+0], av.x,
                      fmaf(wr[kk*6+1], xp * e,
                      fmaf(wr[kk*6+2], av.z,
                      fmaf(wr[kk*6+3], av.w, wr[kk*6+4]))));
            acc[kk] = fmaf(wr[kk*6+5], fmaxf(s, 0.0f), acc[kk]);
        }
        av = nxt;
    }

    #pragma unroll
    for (int kk = 0; kk < 7; kk++)
        red[(w * 7 + kk) * 64 + b] = acc[kk];
    __syncthreads();

    if (w < 7) {
        const int kk = w, k = k0 + kk;
        float sum = 0.0f;
        #pragma unroll
        for (int ww = 0; ww < 16; ww++)
            sum += red[(ww * 7 + kk) * 64 + b];
        part[(size_t)lh * (NB * NK * ND) + ((size_t)b * NK + k) * ND + d] = sum;
    }
}

// ---------------- K3: epilogue — combine halves + bias + relu -----------------------------
__global__ __launch_bounds__(512) void alnn_epi(
    const float* __restrict__ part, const float* __restrict__ b_v,
    float* __restrict__ out)
{
    const int i = blockIdx.x * 512 + threadIdx.x;
    if (i < NB * NK * ND) {
        const int r = i % (NK * ND);                     // = k*ND + d
        const float s = part[i] + part[NB * NK * ND + i];
        out[i] = fmaxf(s + 200.0f * b_v[r], 0.0f);
    }
}

// ---------------- legacy fallback (proven round-1 kernel) ----------------------------------
__global__ __launch_bounds__(256) void alnn_fused_kernel(
    const float* __restrict__ X, const float* __restrict__ T,
    const float* __restrict__ M, const float* __restrict__ PD,
    const float* __restrict__ alpha, const float* __restrict__ w_v,
    const float4* __restrict__ w_t, const float* __restrict__ b_v,
    const float* __restrict__ b_t, float* __restrict__ out)
{
    const int bk = blockIdx.x;
    const int k  = bk % NK;
    const int b  = bk / NK;
    const int t  = threadIdx.x;

    __shared__ float part[7][ND];

    const float alpha_k = fmaxf(alpha[k], 0.0f);
    const float refk    = (float)k;

    if (t < 7 * ND) {
        const int d = t % ND;
        const int j = t / ND;
        const float*  Xp  = X   + (size_t)b * LD + d;
        const float*  Tp  = T   + (size_t)b * LD + d;
        const float*  Mp  = M   + (size_t)b * LD + d;
        const float*  Pp  = PD  + (size_t)b * LD + d;
        const float*  wvp = w_v + (size_t)k * LD + d;
        const float*  btp = b_t + (size_t)k * LD + d;
        const float4* wtp = w_t + (size_t)k * LD + d;

        float acc = 0.0f;
        for (int l = j; l < NL; l += 7) {
            const int o = l * ND;
            const float x  = Xp[o];
            const float tt = Tp[o];
            const float m  = Mp[o];
            const float pd = Pp[o];
            const float4 wv4 = wtp[o];
            const float bt = btp[o];
            const float dist  = fabsf(tt - refk);
            const float e     = __expf(-alpha_k * dist);
            const float inten = fmaxf(x * e, 0.0f);
            float s = fmaf(wv4.x, x, fmaf(wv4.y, inten, fmaf(wv4.z, m, fmaf(wv4.w, pd, 4.0f * bt))));
            s = fmaxf(s, 0.0f);
            acc = fmaf(wvp[o], s, acc);
        }
        part[j][d] = acc;
    }
    __syncthreads();

    if (t < ND) {
        float sum = 0.0f;
        #pragma unroll
        for (int j = 0; j < 7; ++j) sum += part[j][t];
        sum += (float)NL * b_v[k * ND + t];
        out[(size_t)bk * ND + t] = fmaxf(sum, 0.0f);
    }
}

extern "C" void kernel_launch(void* const* d_in, const int* in_sizes, int n_in,
                              void* d_out, int out_size, void* d_ws, size_t ws_size,
                              hipStream_t stream) {
    const float* X     = (const float*)d_in[0];
    const float* T     = (const float*)d_in[1];
    const float* M     = (const float*)d_in[2];
    const float* PD    = (const float*)d_in[3];
    const float* alpha = (const float*)d_in[4];
    const float* w_v   = (const float*)d_in[5];
    const float* w_t   = (const float*)d_in[6];
    const float* b_v   = (const float*)d_in[7];
    const float* b_t   = (const float*)d_in[8];
    float* out = (float*)d_out;
    float* ws  = (float*)d_ws;

    if (ws_size >= WS_NEED_BYTES) {
        alnn_pack<<<450, 256, 0, stream>>>(X, T, M, PD, w_v, (const float4*)w_t, b_t, ws);
        alnn_main10<<<504, 1024, 0, stream>>>(ws, alpha, ws + PART_OFF);
        alnn_epi<<<(NB * NK * ND + 511) / 512, 512, 0, stream>>>(ws + PART_OFF, b_v, out);
    } else {
        alnn_fused_kernel<<<NB * NK, 256, 0, stream>>>(
            X, T, M, PD, alpha, w_v, (const float4*)w_t, b_v, b_t, out);
    }
}